// Round 7
// baseline (2049.446 us; speedup 1.0000x reference)
//
#include <hip/hip_runtime.h>

// KMeans++ init on MI355X. B=32, N=16384, D=64, K=64.
// data: (B,N,D) fp32; first_idx: (B,) int32. Output centers: (B,K,D) fp32.
//
// Persistent kernel (cooperative launch for co-residency only; no grid.sync,
// no fences). Cross-block sync per step = write-once packed (dist,idx) u64
// slot per (step,batch,block), relaxed agent-scope atomics (round-4 win:
// keeps read-only data resident in L2/L3 across steps; round-3's grid.sync
// L2-flush was 12 ms).
//
// Round-7 delta vs round-6: pin waves/EU to EXACTLY [4,4] via
// __attribute__((amdgpu_waves_per_eu(4,4))). Rounds 5/6 proved that
// __launch_bounds__(256, w) sets only the MINIMUM waves/EU: the backend
// targeted the top of the range (8/EU -> 64-VGPR budget) and spilled the
// depth-16 pipeline to scratch (WRITE_SIZE 127 MB, VGPR_Count 64). Pinning
// [4,4] gives a firm 128-VGPR budget so xb[16] (64 VGPRs) stays in registers.
//
// DEPTH=16 rotating load pipeline with cross-step prefetch: addresses are
// step-invariant and DEPTH | npass, so tail-pass prefetches of step k are
// exactly the head passes of step k+1 (in flight during poll + staging).
//
// Packing: (float_bits(val)<<32) | (u32)~idx; val>=0 so u64 order == argmax
// with numpy tie-break (smaller index). Low word never 0 -> 0 = "unwritten".

#define B_   32
#define N_   16384
#define D_   64
#define K_   64
#define T_   256
#define WPB  4
#define GMAX 64                       // slot stride (max blocks per batch)
#define SLOTS_PER_K (B_ * GMAX)

typedef unsigned long long u64;

// numpy argmax semantics: on equal value keep the smaller index.
__device__ __forceinline__ void amax_comb(float& v, int& i, float v2, int i2) {
    if (v2 > v || (v2 == v && i2 < i)) { v = v2; i = i2; }
}

__global__ void kmpp_zero_slots(u64* __restrict__ slots, int n) {
    int i = blockIdx.x * blockDim.x + threadIdx.x;
    if (i < n) slots[i] = 0ULL;
}

// ------------------------- persistent primary path --------------------------

template <int GSHIFT, int DEPTH>
__global__ __launch_bounds__(T_)
__attribute__((amdgpu_waves_per_eu(4, 4)))   // firm 128-VGPR budget, no spill
void kmpp_coop(
    const float* __restrict__ data, const int* __restrict__ first_idx,
    u64* __restrict__ slots, float* __restrict__ centers)
{
    constexpr int gpb   = 1 << GSHIFT;   // blocks per batch
    constexpr int chunk = N_ >> GSHIFT;  // points per block
    constexpr int npass = chunk / 16;    // 4 points per pass per wave
    constexpr int ppw   = chunk / 4;     // points per wave
    static_assert(npass % DEPTH == 0, "cross-step prefetch needs DEPTH | npass");

    const int b    = blockIdx.x >> GSHIFT;
    const int g    = blockIdx.x & (gpb - 1);
    const int wave = threadIdx.x >> 6;
    const int lane = threadIdx.x & 63;
    const int sub  = lane >> 4;          // point-in-pass 0..3
    const int d4   = lane & 15;          // float4 index in the 64-elem row

    const float* __restrict__ bdata = data + (size_t)b * N_ * D_;
    const float4* __restrict__ rowp = (const float4*)bdata;
    const int lbase = wave * ppw;
    const int gbase = g * chunk;

    __shared__ float  md[chunk];         // running min sq-dist (block-private)
    __shared__ float4 csh[D_ / 4];
    __shared__ float  red_v[WPB];
    __shared__ int    red_i[WPB];
    __shared__ int    s_ci;

    for (int i = threadIdx.x; i < chunk; i += T_) md[i] = 3.4e38f;

    // Prime the pipeline: loads for passes 0..DEPTH-1 (same addresses every
    // step; per-step re-priming happens in the tail of the compute loop).
    float4 xb[DEPTH];
    #pragma unroll
    for (int t = 0; t < DEPTH; ++t)
        xb[t] = rowp[(size_t)(gbase + lbase + t * 4 + sub) * 16 + d4];

    for (int k = 0; k < K_; ++k) {
        // ---- this step's center index (pipeline loads already in flight,
        //      overlapping this poll + staging) ----
        if (k == 0) {
            if (threadIdx.x == 0) s_ci = first_idx[b];
        } else if (wave == 0) {
            u64 pk = 0;
            if (lane < gpb) {
                const u64* slot = slots + (size_t)(k - 1) * SLOTS_PER_K
                                        + b * GMAX + lane;
                do {
                    pk = __hip_atomic_load(slot, __ATOMIC_RELAXED,
                                           __HIP_MEMORY_SCOPE_AGENT);
                } while (pk == 0ULL);
            }
            #pragma unroll
            for (int m = 1; m < 64; m <<= 1) {
                u64 o = __shfl_xor(pk, m, 64);
                if (o > pk) pk = o;      // max packed == numpy argmax
            }
            if (lane == 0) s_ci = (int)(~(unsigned)pk);
        }
        __syncthreads();
        const int ci = s_ci;

        // ---- stage center row; block g==0 writes the output row ----
        if (threadIdx.x < D_ / 4)
            csh[threadIdx.x] = ((const float4*)(bdata + (size_t)ci * D_))[threadIdx.x];
        __syncthreads();
        if (g == 0 && threadIdx.x < D_ / 4)
            ((float4*)(centers + ((size_t)b * K_ + k) * D_))[threadIdx.x] = csh[threadIdx.x];
        if (k == K_ - 1) break;          // uniform exit

        // ---- min_d update + local argmax; rotating DEPTH-deep pipeline.
        //      Prefetch target (t+DEPTH) mod npass: tail passes re-prime the
        //      head passes of the NEXT step (same addresses). ----
        const float4 c = csh[d4];
        float bv = -1.f; int bi = 0x7fffffff;
        #pragma unroll
        for (int t = 0; t < npass; ++t) {
            float4 x = xb[t % DEPTH];
            const int nt = (t + DEPTH) & (npass - 1);
            xb[t % DEPTH] = rowp[(size_t)(gbase + lbase + nt * 4 + sub) * 16 + d4];
            float dx = x.x - c.x, dy = x.y - c.y, dz = x.z - c.z, dw = x.w - c.w;
            float s = fmaf(dx, dx, fmaf(dy, dy, fmaf(dz, dz, dw * dw)));
            s += __shfl_xor(s, 1, 64);
            s += __shfl_xor(s, 2, 64);
            s += __shfl_xor(s, 4, 64);
            s += __shfl_xor(s, 8, 64);   // 16-lane sub-group holds d(p)
            const int lp = lbase + t * 4 + sub;
            float nv = fminf(md[lp], s);
            if (d4 == 0) md[lp] = nv;
            amax_comb(bv, bi, nv, gbase + lp);   // sub-group dups: harmless
        }
        #pragma unroll
        for (int m = 1; m < 64; m <<= 1) {
            float v2 = __shfl_xor(bv, m, 64);
            int   i2 = __shfl_xor(bi, m, 64);
            amax_comb(bv, bi, v2, i2);
        }
        if (lane == 0) { red_v[wave] = bv; red_i[wave] = bi; }
        __syncthreads();
        if (threadIdx.x == 0) {
            #pragma unroll
            for (int w = 1; w < WPB; ++w) amax_comb(bv, bi, red_v[w], red_i[w]);
            u64 pk = ((u64)__float_as_uint(bv) << 32) | (unsigned)(~bi);
            __hip_atomic_store(slots + (size_t)k * SLOTS_PER_K + b * GMAX + g,
                               pk, __ATOMIC_RELAXED, __HIP_MEMORY_SCOPE_AGENT);
        }
        // red_* reuse in step k+1 is ordered by the staging barriers above.
    }
}

// ------------------- round-1 multi-launch fallback path ---------------------
// Proven correct (absmax 0, 1827 us). Used only if coop co-residency fails.

#define FG   16
#define FPPT 4
#define FCHUNK (N_ / FG)

__device__ __forceinline__ void fb_block_argmax_store(
    float v, int i, int b, int g, int parity,
    float* __restrict__ pval, int* __restrict__ pidx,
    float* red_v, int* red_i)
{
    #pragma unroll
    for (int off = 32; off > 0; off >>= 1) {
        float v2 = __shfl_down(v, off, 64);
        int   i2 = __shfl_down(i, off, 64);
        amax_comb(v, i, v2, i2);
    }
    int lane = threadIdx.x & 63;
    int wave = threadIdx.x >> 6;
    if (lane == 0) { red_v[wave] = v; red_i[wave] = i; }
    __syncthreads();
    if (threadIdx.x == 0) {
        #pragma unroll
        for (int w = 1; w < T_ / 64; ++w) amax_comb(v, i, red_v[w], red_i[w]);
        pval[(b * 2 + parity) * FG + g] = v;
        pidx[(b * 2 + parity) * FG + g] = i;
    }
}

__device__ __forceinline__ float fb_dist2(const float4* __restrict__ row,
                                          const float4* csh)
{
    float ax = 0.f, ay = 0.f, az = 0.f, aw = 0.f;
    #pragma unroll
    for (int j = 0; j < D_ / 4; ++j) {
        float4 x = row[j];
        float4 c = csh[j];
        float dx = x.x - c.x, dy = x.y - c.y, dz = x.z - c.z, dw = x.w - c.w;
        ax = fmaf(dx, dx, ax);
        ay = fmaf(dy, dy, ay);
        az = fmaf(dz, dz, az);
        aw = fmaf(dw, dw, aw);
    }
    return (ax + ay) + (az + aw);
}

__global__ __launch_bounds__(T_) void kmpp_init(
    const float* __restrict__ data, const int* __restrict__ first_idx,
    float* __restrict__ min_d, float* __restrict__ pval, int* __restrict__ pidx,
    float* __restrict__ centers)
{
    const int blk = blockIdx.x;
    const int b = blk / FG, g = blk % FG;
    __shared__ float4 csh[D_ / 4];
    __shared__ float red_v[T_ / 64];
    __shared__ int   red_i[T_ / 64];

    const int ci = first_idx[b];
    const float4* crow = (const float4*)(data + ((size_t)b * N_ + ci) * D_);
    if (threadIdx.x < D_ / 4) csh[threadIdx.x] = crow[threadIdx.x];
    __syncthreads();
    if (g == 0 && threadIdx.x < D_ / 4)
        ((float4*)(centers + (size_t)b * K_ * D_))[threadIdx.x] = csh[threadIdx.x];

    float best_v = -1.f; int best_i = 0;
    for (int m = 0; m < FPPT; ++m) {
        const int p = g * FCHUNK + m * T_ + threadIdx.x;
        const float4* row = (const float4*)(data + ((size_t)b * N_ + p) * D_);
        float d = fb_dist2(row, csh);
        min_d[(size_t)b * N_ + p] = d;
        amax_comb(best_v, best_i, d, p);
    }
    fb_block_argmax_store(best_v, best_i, b, g, 0, pval, pidx, red_v, red_i);
}

__global__ __launch_bounds__(T_) void kmpp_step(
    const float* __restrict__ data, float* __restrict__ min_d,
    float* __restrict__ pval, int* __restrict__ pidx,
    float* __restrict__ centers, int k)
{
    const int blk = blockIdx.x;
    const int b = blk / FG, g = blk % FG;
    const int pin = (k - 1) & 1, pout = k & 1;
    __shared__ float4 csh[D_ / 4];
    __shared__ float red_v[T_ / 64];
    __shared__ int   red_i[T_ / 64];
    __shared__ int   sidx;

    if (threadIdx.x == 0) {
        float v = pval[(b * 2 + pin) * FG];
        int   i = pidx[(b * 2 + pin) * FG];
        for (int gg = 1; gg < FG; ++gg)
            amax_comb(v, i, pval[(b * 2 + pin) * FG + gg], pidx[(b * 2 + pin) * FG + gg]);
        sidx = i;
    }
    __syncthreads();
    const int ci = sidx;
    const float4* crow = (const float4*)(data + ((size_t)b * N_ + ci) * D_);
    if (threadIdx.x < D_ / 4) csh[threadIdx.x] = crow[threadIdx.x];
    __syncthreads();
    if (g == 0 && threadIdx.x < D_ / 4)
        ((float4*)(centers + ((size_t)b * K_ + k) * D_))[threadIdx.x] = csh[threadIdx.x];

    if (k == K_ - 1) return;

    float best_v = -1.f; int best_i = 0;
    for (int m = 0; m < FPPT; ++m) {
        const int p = g * FCHUNK + m * T_ + threadIdx.x;
        const float4* row = (const float4*)(data + ((size_t)b * N_ + p) * D_);
        float d = fb_dist2(row, csh);
        const size_t off = (size_t)b * N_ + p;
        float nv = fminf(min_d[off], d);
        min_d[off] = nv;
        amax_comb(best_v, best_i, nv, p);
    }
    fb_block_argmax_store(best_v, best_i, b, g, pout, pval, pidx, red_v, red_i);
}

// ---------------------------------------------------------------------------

extern "C" void kernel_launch(void* const* d_in, const int* in_sizes, int n_in,
                              void* d_out, int out_size, void* d_ws, size_t ws_size,
                              hipStream_t stream)
{
    const float* data      = (const float*)d_in[0];
    const int*   first_idx = (const int*)d_in[1];
    float*       centers   = (float*)d_out;

    // Exclusive ws layouts per path:
    //   coop:     slots[K*B*64] u64 (1 MB)
    //   fallback: min_d[B*N] f32 | pval[B*2*FG] | pidx[B*2*FG]
    u64*   slots = (u64*)d_ws;
    float* min_d = (float*)d_ws;
    float* pval  = min_d + (size_t)B_ * N_;
    int*   pidx  = (int*)(pval + B_ * 2 * FG);

    // Capture-safe occupancy queries (pure host, deterministic every call).
    int occ5 = 0, occ4 = 0;
    (void)hipOccupancyMaxActiveBlocksPerMultiprocessor(&occ5, kmpp_coop<5, 16>, T_, 0);
    (void)hipOccupancyMaxActiveBlocksPerMultiprocessor(&occ4, kmpp_coop<4, 16>, T_, 0);

    const void* kfn = nullptr;
    int gshift = 0;
    if (occ5 >= 4)      { kfn = (const void*)kmpp_coop<5, 16>; gshift = 5; } // 1024 blk
    else if (occ4 >= 2) { kfn = (const void*)kmpp_coop<4, 16>; gshift = 4; } //  512 blk

    if (kfn) {
        const int nslots = K_ * SLOTS_PER_K;
        hipLaunchKernelGGL(kmpp_zero_slots, dim3((nslots + T_ - 1) / T_), dim3(T_),
                           0, stream, slots, nslots);
        void* args[] = { (void*)&data, (void*)&first_idx,
                         (void*)&slots, (void*)&centers };
        hipError_t err = hipLaunchCooperativeKernel(
            kfn, dim3(B_ << gshift), dim3(T_), args, 0, stream);
        if (err == hipSuccess) return;
        (void)hipGetLastError();   // clear sticky error, fall through
    }

    // Fallback: proven multi-launch path.
    dim3 grid(B_ * FG), block(T_);
    hipLaunchKernelGGL(kmpp_init, grid, block, 0, stream,
                       data, first_idx, min_d, pval, pidx, centers);
    for (int k = 1; k < K_; ++k) {
        hipLaunchKernelGGL(kmpp_step, grid, block, 0, stream,
                           data, min_d, pval, pidx, centers, k);
    }
}

// Round 8
// 1434.784 us; speedup vs baseline: 1.4284x; 1.4284x over previous
//
#include <hip/hip_runtime.h>

// KMeans++ init on MI355X. B=32, N=16384, D=64, K=64.
// data: (B,N,D) fp32; first_idx: (B,) int32. Output centers: (B,K,D) fp32.
//
// Persistent kernel (cooperative launch for co-residency only; no grid.sync,
// no fences). Cross-block sync per step = write-once packed (dist,idx) u64
// slot per (step,batch,block), relaxed agent-scope atomics (round-4 win).
//
// Round-8 delta vs round-4 (service-rate wall diagnosis):
//   R4's 18.7 us/step == 128 MB/step / 6.8 TB/s combined L1+L2+L3 service
//   rate -- a bandwidth wall, not latency (R5-R7 MLP attempts all failed or
//   regressed; allocator refuses >64 VGPRs, so register pipelines spill).
//   Lever: fewer bytes. Pin each wave's first PINPASS=8 passes (32 points,
//   8 KB) in LDS -> 32 KB/block = 32 MB chip-wide = 25% of the dataset,
//   copied once, served from LDS for all 63 steps. Identical arithmetic
//   order and fp32 bits -> argmax decisions unchanged (absmax 0).
//   Global-pass pipeline (depth 4, the proven R4 shape -- VGPR 36, no spill)
//   is primed at step-top so its latency hides behind the LDS passes.
//
// Packing: (float_bits(val)<<32) | (u32)~idx; val>=0 so u64 order == argmax
// with numpy tie-break (smaller index). Low word never 0 -> 0 = "unwritten".

#define B_   32
#define N_   16384
#define D_   64
#define K_   64
#define T_   256
#define WPB  4
#define GMAX 64                       // slot stride (max blocks per batch)
#define SLOTS_PER_K (B_ * GMAX)

typedef unsigned long long u64;

// numpy argmax semantics: on equal value keep the smaller index.
__device__ __forceinline__ void amax_comb(float& v, int& i, float v2, int i2) {
    if (v2 > v || (v2 == v && i2 < i)) { v = v2; i = i2; }
}

__global__ void kmpp_zero_slots(u64* __restrict__ slots, int n) {
    int i = blockIdx.x * blockDim.x + threadIdx.x;
    if (i < n) slots[i] = 0ULL;
}

// ------------------------- persistent primary path --------------------------

template <int GSHIFT, int PINPASS>
__global__ __launch_bounds__(T_, 4) void kmpp_coop(
    const float* __restrict__ data, const int* __restrict__ first_idx,
    u64* __restrict__ slots, float* __restrict__ centers)
{
    constexpr int gpb   = 1 << GSHIFT;   // blocks per batch
    constexpr int chunk = N_ >> GSHIFT;  // points per block
    constexpr int npass = chunk / 16;    // 4 points per pass per wave
    constexpr int ppw   = chunk / 4;     // points per wave
    constexpr int npin4 = WPB * PINPASS * 4 * 16;  // pinned float4 count
    static_assert(PINPASS % 4 == 0 && PINPASS + 4 <= npass, "pipeline bounds");

    const int b    = blockIdx.x >> GSHIFT;
    const int g    = blockIdx.x & (gpb - 1);
    const int wave = threadIdx.x >> 6;
    const int lane = threadIdx.x & 63;
    const int sub  = lane >> 4;          // point-in-pass 0..3
    const int d4   = lane & 15;          // float4 index in the 64-elem row

    const float* __restrict__ bdata = data + (size_t)b * N_ * D_;
    const float4* __restrict__ rowp = (const float4*)bdata;
    const int lbase = wave * ppw;
    const int gbase = g * chunk;

    __shared__ float  md[chunk];         // running min sq-dist (block-private)
    __shared__ float4 pinned[npin4];     // 32 KB: first PINPASS passes / wave
    __shared__ float4 csh[D_ / 4];
    __shared__ float  red_v[WPB];
    __shared__ int    red_i[WPB];
    __shared__ int    s_ci;

    for (int i = threadIdx.x; i < chunk; i += T_) md[i] = 3.4e38f;

    // One-time fill of the pinned tile (exact fp32 copies; layout matches the
    // compute-side index so reads are contiguous 1 KB per wave).
    for (int l = threadIdx.x; l < npin4; l += T_) {
        const int dd = l & 15;
        const int s  = l >> 4;                 // (w*PINPASS + t)*4 + sub
        const int w  = s / (PINPASS * 4);
        const int r  = s - w * (PINPASS * 4);
        const int lp = w * ppw + (r >> 2) * 4 + (r & 3);
        pinned[l] = rowp[(size_t)(gbase + lp) * 16 + dd];
    }
    // Ordered before first use by the first __syncthreads in the k-loop.

    for (int k = 0; k < K_; ++k) {
        // ---- prime the global-pass pipeline (addresses independent of ci;
        //      loads fly during the poll + staging + LDS passes) ----
        float4 xb[4];
        #pragma unroll
        for (int j = 0; j < 4; ++j)
            xb[j] = rowp[(size_t)(gbase + lbase + (PINPASS + j) * 4 + sub) * 16 + d4];

        // ---- this step's center index ----
        if (k == 0) {
            if (threadIdx.x == 0) s_ci = first_idx[b];
        } else if (wave == 0) {
            u64 pk = 0;
            if (lane < gpb) {
                const u64* slot = slots + (size_t)(k - 1) * SLOTS_PER_K
                                        + b * GMAX + lane;
                do {
                    pk = __hip_atomic_load(slot, __ATOMIC_RELAXED,
                                           __HIP_MEMORY_SCOPE_AGENT);
                } while (pk == 0ULL);
            }
            #pragma unroll
            for (int m = 1; m < 64; m <<= 1) {
                u64 o = __shfl_xor(pk, m, 64);
                if (o > pk) pk = o;      // max packed == numpy argmax
            }
            if (lane == 0) s_ci = (int)(~(unsigned)pk);
        }
        __syncthreads();
        const int ci = s_ci;

        // ---- stage center row; block g==0 writes the output row ----
        if (threadIdx.x < D_ / 4)
            csh[threadIdx.x] = ((const float4*)(bdata + (size_t)ci * D_))[threadIdx.x];
        __syncthreads();
        if (g == 0 && threadIdx.x < D_ / 4)
            ((float4*)(centers + ((size_t)b * K_ + k) * D_))[threadIdx.x] = csh[threadIdx.x];
        if (k == K_ - 1) break;          // uniform exit

        const float4 c = csh[d4];
        float bv = -1.f; int bi = 0x7fffffff;

        // ---- Loop A: pinned LDS passes (t = 0..PINPASS-1) ----
        #pragma unroll
        for (int t = 0; t < PINPASS; ++t) {
            float4 x = pinned[((wave * PINPASS + t) * 4 + sub) * 16 + d4];
            float dx = x.x - c.x, dy = x.y - c.y, dz = x.z - c.z, dw = x.w - c.w;
            float s = fmaf(dx, dx, fmaf(dy, dy, fmaf(dz, dz, dw * dw)));
            s += __shfl_xor(s, 1, 64);
            s += __shfl_xor(s, 2, 64);
            s += __shfl_xor(s, 4, 64);
            s += __shfl_xor(s, 8, 64);   // 16-lane sub-group holds d(p)
            const int lp = lbase + t * 4 + sub;
            float nv = fminf(md[lp], s);
            if (d4 == 0) md[lp] = nv;
            amax_comb(bv, bi, nv, gbase + lp);   // sub-group dups: harmless
        }

        // ---- Loop B: streamed global passes, depth-4 rotating pipeline
        //      ((t-PINPASS)&3 == t&3 since PINPASS%4==0) ----
        #pragma unroll 4
        for (int t = PINPASS; t < npass; ++t) {
            float4 x = xb[t & 3];
            if (t + 4 < npass)
                xb[t & 3] = rowp[(size_t)(gbase + lbase + (t + 4) * 4 + sub) * 16 + d4];
            float dx = x.x - c.x, dy = x.y - c.y, dz = x.z - c.z, dw = x.w - c.w;
            float s = fmaf(dx, dx, fmaf(dy, dy, fmaf(dz, dz, dw * dw)));
            s += __shfl_xor(s, 1, 64);
            s += __shfl_xor(s, 2, 64);
            s += __shfl_xor(s, 4, 64);
            s += __shfl_xor(s, 8, 64);
            const int lp = lbase + t * 4 + sub;
            float nv = fminf(md[lp], s);
            if (d4 == 0) md[lp] = nv;
            amax_comb(bv, bi, nv, gbase + lp);
        }

        #pragma unroll
        for (int m = 1; m < 64; m <<= 1) {
            float v2 = __shfl_xor(bv, m, 64);
            int   i2 = __shfl_xor(bi, m, 64);
            amax_comb(bv, bi, v2, i2);
        }
        if (lane == 0) { red_v[wave] = bv; red_i[wave] = bi; }
        __syncthreads();
        if (threadIdx.x == 0) {
            #pragma unroll
            for (int w = 1; w < WPB; ++w) amax_comb(bv, bi, red_v[w], red_i[w]);
            u64 pk = ((u64)__float_as_uint(bv) << 32) | (unsigned)(~bi);
            __hip_atomic_store(slots + (size_t)k * SLOTS_PER_K + b * GMAX + g,
                               pk, __ATOMIC_RELAXED, __HIP_MEMORY_SCOPE_AGENT);
        }
        // red_* reuse in step k+1 is ordered by the staging barriers above.
    }
}

// ------------------- round-1 multi-launch fallback path ---------------------
// Proven correct (absmax 0, 1827 us). Used only if coop co-residency fails.

#define FG   16
#define FPPT 4
#define FCHUNK (N_ / FG)

__device__ __forceinline__ void fb_block_argmax_store(
    float v, int i, int b, int g, int parity,
    float* __restrict__ pval, int* __restrict__ pidx,
    float* red_v, int* red_i)
{
    #pragma unroll
    for (int off = 32; off > 0; off >>= 1) {
        float v2 = __shfl_down(v, off, 64);
        int   i2 = __shfl_down(i, off, 64);
        amax_comb(v, i, v2, i2);
    }
    int lane = threadIdx.x & 63;
    int wave = threadIdx.x >> 6;
    if (lane == 0) { red_v[wave] = v; red_i[wave] = i; }
    __syncthreads();
    if (threadIdx.x == 0) {
        #pragma unroll
        for (int w = 1; w < T_ / 64; ++w) amax_comb(v, i, red_v[w], red_i[w]);
        pval[(b * 2 + parity) * FG + g] = v;
        pidx[(b * 2 + parity) * FG + g] = i;
    }
}

__device__ __forceinline__ float fb_dist2(const float4* __restrict__ row,
                                          const float4* csh)
{
    float ax = 0.f, ay = 0.f, az = 0.f, aw = 0.f;
    #pragma unroll
    for (int j = 0; j < D_ / 4; ++j) {
        float4 x = row[j];
        float4 c = csh[j];
        float dx = x.x - c.x, dy = x.y - c.y, dz = x.z - c.z, dw = x.w - c.w;
        ax = fmaf(dx, dx, ax);
        ay = fmaf(dy, dy, ay);
        az = fmaf(dz, dz, az);
        aw = fmaf(dw, dw, aw);
    }
    return (ax + ay) + (az + aw);
}

__global__ __launch_bounds__(T_) void kmpp_init(
    const float* __restrict__ data, const int* __restrict__ first_idx,
    float* __restrict__ min_d, float* __restrict__ pval, int* __restrict__ pidx,
    float* __restrict__ centers)
{
    const int blk = blockIdx.x;
    const int b = blk / FG, g = blk % FG;
    __shared__ float4 csh[D_ / 4];
    __shared__ float red_v[T_ / 64];
    __shared__ int   red_i[T_ / 64];

    const int ci = first_idx[b];
    const float4* crow = (const float4*)(data + ((size_t)b * N_ + ci) * D_);
    if (threadIdx.x < D_ / 4) csh[threadIdx.x] = crow[threadIdx.x];
    __syncthreads();
    if (g == 0 && threadIdx.x < D_ / 4)
        ((float4*)(centers + (size_t)b * K_ * D_))[threadIdx.x] = csh[threadIdx.x];

    float best_v = -1.f; int best_i = 0;
    for (int m = 0; m < FPPT; ++m) {
        const int p = g * FCHUNK + m * T_ + threadIdx.x;
        const float4* row = (const float4*)(data + ((size_t)b * N_ + p) * D_);
        float d = fb_dist2(row, csh);
        min_d[(size_t)b * N_ + p] = d;
        amax_comb(best_v, best_i, d, p);
    }
    fb_block_argmax_store(best_v, best_i, b, g, 0, pval, pidx, red_v, red_i);
}

__global__ __launch_bounds__(T_) void kmpp_step(
    const float* __restrict__ data, float* __restrict__ min_d,
    float* __restrict__ pval, int* __restrict__ pidx,
    float* __restrict__ centers, int k)
{
    const int blk = blockIdx.x;
    const int b = blk / FG, g = blk % FG;
    const int pin = (k - 1) & 1, pout = k & 1;
    __shared__ float4 csh[D_ / 4];
    __shared__ float red_v[T_ / 64];
    __shared__ int   red_i[T_ / 64];
    __shared__ int   sidx;

    if (threadIdx.x == 0) {
        float v = pval[(b * 2 + pin) * FG];
        int   i = pidx[(b * 2 + pin) * FG];
        for (int gg = 1; gg < FG; ++gg)
            amax_comb(v, i, pval[(b * 2 + pin) * FG + gg], pidx[(b * 2 + pin) * FG + gg]);
        sidx = i;
    }
    __syncthreads();
    const int ci = sidx;
    const float4* crow = (const float4*)(data + ((size_t)b * N_ + ci) * D_);
    if (threadIdx.x < D_ / 4) csh[threadIdx.x] = crow[threadIdx.x];
    __syncthreads();
    if (g == 0 && threadIdx.x < D_ / 4)
        ((float4*)(centers + ((size_t)b * K_ + k) * D_))[threadIdx.x] = csh[threadIdx.x];

    if (k == K_ - 1) return;

    float best_v = -1.f; int best_i = 0;
    for (int m = 0; m < FPPT; ++m) {
        const int p = g * FCHUNK + m * T_ + threadIdx.x;
        const float4* row = (const float4*)(data + ((size_t)b * N_ + p) * D_);
        float d = fb_dist2(row, csh);
        const size_t off = (size_t)b * N_ + p;
        float nv = fminf(min_d[off], d);
        min_d[off] = nv;
        amax_comb(best_v, best_i, nv, p);
    }
    fb_block_argmax_store(best_v, best_i, b, g, pout, pval, pidx, red_v, red_i);
}

// ---------------------------------------------------------------------------

extern "C" void kernel_launch(void* const* d_in, const int* in_sizes, int n_in,
                              void* d_out, int out_size, void* d_ws, size_t ws_size,
                              hipStream_t stream)
{
    const float* data      = (const float*)d_in[0];
    const int*   first_idx = (const int*)d_in[1];
    float*       centers   = (float*)d_out;

    // Exclusive ws layouts per path:
    //   coop:     slots[K*B*64] u64 (1 MB)
    //   fallback: min_d[B*N] f32 | pval[B*2*FG] | pidx[B*2*FG]
    u64*   slots = (u64*)d_ws;
    float* min_d = (float*)d_ws;
    float* pval  = min_d + (size_t)B_ * N_;
    int*   pidx  = (int*)(pval + B_ * 2 * FG);

    // Capture-safe occupancy queries (pure host, deterministic every call).
    int occ5 = 0, occ4 = 0;
    (void)hipOccupancyMaxActiveBlocksPerMultiprocessor(&occ5, kmpp_coop<5, 8>, T_, 0);
    (void)hipOccupancyMaxActiveBlocksPerMultiprocessor(&occ4, kmpp_coop<4, 8>, T_, 0);

    const void* kfn = nullptr;
    int gshift = 0;
    if (occ5 >= 4)      { kfn = (const void*)kmpp_coop<5, 8>; gshift = 5; } // 1024 blk
    else if (occ4 >= 2) { kfn = (const void*)kmpp_coop<4, 8>; gshift = 4; } //  512 blk

    if (kfn) {
        const int nslots = K_ * SLOTS_PER_K;
        hipLaunchKernelGGL(kmpp_zero_slots, dim3((nslots + T_ - 1) / T_), dim3(T_),
                           0, stream, slots, nslots);
        void* args[] = { (void*)&data, (void*)&first_idx,
                         (void*)&slots, (void*)&centers };
        hipError_t err = hipLaunchCooperativeKernel(
            kfn, dim3(B_ << gshift), dim3(T_), args, 0, stream);
        if (err == hipSuccess) return;
        (void)hipGetLastError();   // clear sticky error, fall through
    }

    // Fallback: proven multi-launch path.
    dim3 grid(B_ * FG), block(T_);
    hipLaunchKernelGGL(kmpp_init, grid, block, 0, stream,
                       data, first_idx, min_d, pval, pidx, centers);
    for (int k = 1; k < K_; ++k) {
        hipLaunchKernelGGL(kmpp_step, grid, block, 0, stream,
                           data, min_d, pval, pidx, centers, k);
    }
}